// Round 7
// baseline (3407.578 us; speedup 1.0000x reference)
//
#include <hip/hip_runtime.h>
#include <hip/hip_bf16.h>

#define ELL_D 64   // max in-degree slots; Poisson(16) => P(deg>=64) ~ 2e-18/node
#define FB 16      // ownership-fill blocks (disjoint node ranges -> L2-local scatter)
#define NSL 8      // feature slices == XCD count; slice s lives on XCD s via blockIdx%8

typedef __attribute__((ext_vector_type(8))) short short8;
typedef __attribute__((ext_vector_type(4))) float f32x4;

__device__ __forceinline__ unsigned short f2bf(float f) {
    __hip_bfloat16 h = __float2bfloat16(f);  // RNE
    return *(unsigned short*)&h;
}
__device__ __forceinline__ float bf2f(unsigned short u) {
    unsigned int v = ((unsigned int)u) << 16;
    return __uint_as_float(v);
}

// A is slice-major bf16: element (s, n, c) at s*N*16 + n*16 + c   (c in 0..15)

// ---------------- gemm1 body (f32 vector): A = x @ W0, unscaled ----------------

__device__ __forceinline__ void gemm_body(int bid, const float* __restrict__ H,
                                          const float* __restrict__ W, unsigned short* __restrict__ A,
                                          int N, float4* wl4) {
    int tid = threadIdx.x;
    const float4* __restrict__ W4 = (const float4*)W;
    int tc = tid & 15;
    int tr = tid >> 4;
    int rbase = bid * 64 + tr * 4;

    const float4* __restrict__ H4 = (const float4*)H;
    float acc[4][8] = {};
    int r[4];
#pragma unroll
    for (int j = 0; j < 4; j++) {
        int rr = rbase + j;
        r[j] = (rr < N) ? rr : (N - 1);
    }

    for (int p = 0; p < 2; p++) {
        if (p) __syncthreads();
#pragma unroll
        for (int i = 0; i < 8; i++) wl4[i * 256 + tid] = W4[p * 2048 + i * 256 + tid];
        __syncthreads();
#pragma unroll 4
        for (int k4 = 0; k4 < 16; k4++) {
            union { float4 v; float f[4]; } hu[4];
#pragma unroll
            for (int j = 0; j < 4; j++) hu[j].v = H4[r[j] * 32 + p * 16 + k4];
#pragma unroll
            for (int kk = 0; kk < 4; kk++) {
                float4 w0 = wl4[(k4 * 4 + kk) * 32 + tc];
                float4 w1 = wl4[(k4 * 4 + kk) * 32 + 16 + tc];
#pragma unroll
                for (int j = 0; j < 4; j++) {
                    float h = hu[j].f[kk];
                    acc[j][0] = fmaf(h, w0.x, acc[j][0]);
                    acc[j][1] = fmaf(h, w0.y, acc[j][1]);
                    acc[j][2] = fmaf(h, w0.z, acc[j][2]);
                    acc[j][3] = fmaf(h, w0.w, acc[j][3]);
                    acc[j][4] = fmaf(h, w1.x, acc[j][4]);
                    acc[j][5] = fmaf(h, w1.y, acc[j][5]);
                    acc[j][6] = fmaf(h, w1.z, acc[j][6]);
                    acc[j][7] = fmaf(h, w1.w, acc[j][7]);
                }
            }
        }
    }

    // slice-major store: cols 4tc..4tc+3 -> slice tc>>2; cols 64+4tc.. -> slice 4+(tc>>2)
    int s0 = tc >> 2, off = (4 * tc) & 15;
#pragma unroll
    for (int j = 0; j < 4; j++) {
        int rr = rbase + j;
        if (rr < N) {
            *(ushort4*)(A + ((size_t)s0 * N + rr) * 16 + off) =
                make_ushort4(f2bf(acc[j][0]), f2bf(acc[j][1]), f2bf(acc[j][2]), f2bf(acc[j][3]));
            *(ushort4*)(A + ((size_t)(s0 + 4) * N + rr) * 16 + off) =
                make_ushort4(f2bf(acc[j][4]), f2bf(acc[j][5]), f2bf(acc[j][6]), f2bf(acc[j][7]));
        }
    }
}

// ---------------- ownership fill: block owns node range, scans all edges ----------------

__device__ __forceinline__ void fill_own_body(int fb, const int* __restrict__ col, const int* __restrict__ row,
                                              int* __restrict__ cnt, int* __restrict__ ell, int E, int N) {
    int nr = (N + FB - 1) / FB;
    int lo = fb * nr;
    int hi = lo + nr; if (hi > N) hi = N;
    int tid = threadIdx.x;
    int E4 = E >> 2;
    const int4* __restrict__ c4p = (const int4*)col;
    const int4* __restrict__ r4p = (const int4*)row;
    for (int q = tid; q < E4; q += 256) {
        int4 c4 = c4p[q];
        int4 r4 = r4p[q];
        if (c4.x >= lo && c4.x < hi) { int p = atomicAdd(&cnt[c4.x], 1) & 63; ell[c4.x * ELL_D + p] = r4.x; }
        if (c4.y >= lo && c4.y < hi) { int p = atomicAdd(&cnt[c4.y], 1) & 63; ell[c4.y * ELL_D + p] = r4.y; }
        if (c4.z >= lo && c4.z < hi) { int p = atomicAdd(&cnt[c4.z], 1) & 63; ell[c4.z * ELL_D + p] = r4.z; }
        if (c4.w >= lo && c4.w < hi) { int p = atomicAdd(&cnt[c4.w], 1) & 63; ell[c4.w * ELL_D + p] = r4.w; }
    }
    int rem = E & 3;
    if (tid < rem) {
        int e = E4 * 4 + tid;
        int c = col[e];
        if (c >= lo && c < hi) { int p = atomicAdd(&cnt[c], 1) & 63; ell[c * ELL_D + p] = row[e]; }
    }
}

__global__ __launch_bounds__(256) void k_fused(const float* __restrict__ H, const float* __restrict__ W,
                                               unsigned short* __restrict__ A,
                                               const int* __restrict__ col, const int* __restrict__ row,
                                               int* __restrict__ cnt, int* __restrict__ ell,
                                               int N, int E, int gb) {
    __shared__ float4 wl4[2048];  // 32KB (gemm blocks only)
    if (blockIdx.x < FB) {
        fill_own_body(blockIdx.x, col, row, cnt, ell, E, N);
    } else {
        int gbid = blockIdx.x - FB;
        if (gbid < gb) gemm_body(gbid, H, W, A, N, wl4);
    }
}

// ---------------- W prep: WT (bf16, transposed) for layers 2,3 ----------------
__global__ __launch_bounds__(256) void k_prep_wt(const float* __restrict__ W1, const float* __restrict__ W2,
                                                 unsigned short* __restrict__ WT1, unsigned short* __restrict__ WT2) {
    const float* W = blockIdx.x ? W2 : W1;
    unsigned short* WT = blockIdx.x ? WT2 : WT1;
    for (int i = threadIdx.x; i < 16384; i += 256) {
        int c = i >> 7, k = i & 127;
        WT[i] = f2bf(W[k * 128 + c]);  // WT[c][k] = W[k][c]
    }
}

// ---------------- dinv + scale layer-1 A in place (slice-major linear sweep) ----------------
__global__ __launch_bounds__(256) void k_dinv_scaleA(const int* __restrict__ cnt, float* __restrict__ dinv,
                                                     unsigned short* __restrict__ A, int N) {
    int idx = blockIdx.x * 256 + threadIdx.x;  // ushort2 index
    int tot = N * 64;
    if (idx >= tot) return;
    int per = N * 8;            // ushort2 per slice
    int s = idx / per;
    int rem = idx - s * per;
    int n = rem >> 3;
    float dn = 1.0f / sqrtf((float)(cnt[n] + 1));
    if (s == 0 && (rem & 7) == 0) dinv[n] = dn;
    ushort2* p = (ushort2*)A + idx;
    ushort2 v = *p;
    v.x = f2bf(bf2f(v.x) * dn);
    v.y = f2bf(bf2f(v.y) * dn);
    *p = v;
}

// ---------------- MFMA GEMM (layers 2,3): A'(slice-major) = bf16((Bb @ W) * dinv[row]) ----------------

__global__ __launch_bounds__(256) void k_gemm_mfma(const unsigned short* __restrict__ H,
                                                   const unsigned short* __restrict__ WT,
                                                   const float* __restrict__ dinv,
                                                   unsigned short* __restrict__ A, int N) {
    __shared__ float ep[4 * 16 * 132];  // per-wave 16x128 f32, row stride 132
    int tid = threadIdx.x, w = tid >> 6, l = tid & 63;
    int rbase = blockIdx.x * 64 + w * 16;
    int lrow = l & 15, lk = l >> 4;

    int r = rbase + lrow;
    if (r >= N) r = N - 1;
    const short8* __restrict__ Hp = (const short8*)(H + (size_t)r * 128);
    short8 af[4];
#pragma unroll
    for (int kc = 0; kc < 4; kc++) af[kc] = Hp[kc * 4 + lk];

    f32x4 acc[8];
#pragma unroll
    for (int t = 0; t < 8; t++) {
        f32x4 a = {0.f, 0.f, 0.f, 0.f};
        const short8* __restrict__ Wp = (const short8*)(WT + (size_t)(t * 16 + lrow) * 128);
#pragma unroll
        for (int kc = 0; kc < 4; kc++) {
            short8 bf = Wp[kc * 4 + lk];
            a = __builtin_amdgcn_mfma_f32_16x16x32_bf16(af[kc], bf, a, 0, 0, 0);
        }
        acc[t] = a;
    }

    float* base = ep + w * 2112;
#pragma unroll
    for (int t = 0; t < 8; t++)
#pragma unroll
        for (int j = 0; j < 4; j++)
            base[(4 * lk + j) * 132 + t * 16 + lrow] = acc[t][j];
    __syncthreads();

    int row16 = l >> 2, c0 = (l & 3) * 32;
    int orow = rbase + row16;
    if (orow < N) {
        float dn = dinv[orow];
        const float* src = base + row16 * 132 + c0;
#pragma unroll
        for (int q = 0; q < 4; q++) {
            int cq = c0 + q * 8;
            int sq = cq >> 4, off = cq & 15;
            union { short8 s8; unsigned short u[8]; } pk;
#pragma unroll
            for (int e = 0; e < 8; e++) pk.u[e] = f2bf(src[q * 8 + e] * dn);
            *(short8*)(A + ((size_t)sq * N + orow) * 16 + off) = pk.s8;
        }
    }
}

// ---------------- Aggregation (slice-sharded, L2-resident gathers) ----------------
// block: slice s = blockIdx&7 (XCD-pinned), 16 nodes per block, 4 per wave sequential.
// B[n, 16s..16s+16) = relu(dinv[n]*(sum_slots A_s[src]) + bias_slice), bf16 out.

__global__ __launch_bounds__(256) void k_agg(const unsigned short* __restrict__ A, const int* __restrict__ cnt,
                                             const int* __restrict__ ell, const float* __restrict__ dinv,
                                             const float* __restrict__ bias, unsigned short* __restrict__ Bout, int N) {
    int b = blockIdx.x;
    int s = b & 7;
    int chunk = b >> 3;
    int w = threadIdx.x >> 6, lane = threadIdx.x & 63;
    int g = lane >> 3, c2 = lane & 7;  // group g handles slot g+8i; lane covers 2 cols
    const ushort2* __restrict__ As2 = (const ushort2*)A + (size_t)s * N * 8;
    float2 bb = ((const float2*)(bias + 16 * s))[c2];

    int n0 = chunk * 16 + w * 4;
#pragma unroll
    for (int u = 0; u < 4; u++) {
        int n = n0 + u;
        if (n >= N) break;  // wave-uniform
        int deg = cnt[n];
        int total = deg + 1;  // + virtual self edge at slot==deg
        const int* __restrict__ lst = ell + (size_t)n * ELL_D;

        int sl0 = g, sl1 = g + 8, sl2 = g + 16, sl3 = g + 24;
        int id0 = (sl0 < deg) ? lst[sl0] : n;
        int id1 = (sl1 < deg) ? lst[sl1] : n;
        int id2 = (sl2 < deg) ? lst[sl2] : n;
        int id3 = (sl3 < deg) ? lst[sl3] : n;
        float m0 = (sl0 < total) ? 1.f : 0.f;
        float m1 = (sl1 < total) ? 1.f : 0.f;
        float m2 = (sl2 < total) ? 1.f : 0.f;
        float m3 = (sl3 < total) ? 1.f : 0.f;
        ushort2 v0 = As2[(size_t)id0 * 8 + c2];
        ushort2 v1 = As2[(size_t)id1 * 8 + c2];
        ushort2 v2 = As2[(size_t)id2 * 8 + c2];
        ushort2 v3 = As2[(size_t)id3 * 8 + c2];
        float a0 = fmaf(bf2f(v0.x), m0, 0.f);
        float a1 = fmaf(bf2f(v0.y), m0, 0.f);
        a0 = fmaf(bf2f(v1.x), m1, a0); a1 = fmaf(bf2f(v1.y), m1, a1);
        a0 = fmaf(bf2f(v2.x), m2, a0); a1 = fmaf(bf2f(v2.y), m2, a1);
        a0 = fmaf(bf2f(v3.x), m3, a0); a1 = fmaf(bf2f(v3.y), m3, a1);
        // rare tail (deg >= 32)
        for (int slot = 32 + g; slot < total; slot += 8) {
            int id = (slot < deg) ? lst[slot] : n;
            ushort2 v = As2[(size_t)id * 8 + c2];
            a0 += bf2f(v.x);
            a1 += bf2f(v.y);
        }
        a0 += __shfl_xor(a0, 8, 64);
        a0 += __shfl_xor(a0, 16, 64);
        a0 += __shfl_xor(a0, 32, 64);
        a1 += __shfl_xor(a1, 8, 64);
        a1 += __shfl_xor(a1, 16, 64);
        a1 += __shfl_xor(a1, 32, 64);
        if (g == 0) {
            float dn = dinv[n];
            ushort2 o;
            o.x = f2bf(fmaxf(fmaf(a0, dn, bb.x), 0.f));
            o.y = f2bf(fmaxf(fmaf(a1, dn, bb.y), 0.f));
            ((ushort2*)(Bout + (size_t)n * 128 + 16 * s))[c2] = o;
        }
    }
}

// ---------------- Pool (mean per graph, sorted batch) + head; B is bf16 ----------------

__global__ __launch_bounds__(512) void k_pool(const unsigned short* __restrict__ B, const int* __restrict__ batch,
                                              const float* __restrict__ Wl, const float* __restrict__ bl,
                                              float* __restrict__ out, int N) {
    int g = blockIdx.x;
    int tid = threadIdx.x;
    int k = tid & 127, h = tid >> 7;  // h in 0..3
    __shared__ int se[2];
    __shared__ float red[4][128];
    if (tid < 2) {
        int target = g + tid;  // lower_bound(batch, target)
        int lo = 0, hi = N;
        while (lo < hi) {
            int mid = (lo + hi) >> 1;
            if (batch[mid] < target) lo = mid + 1; else hi = mid;
        }
        se[tid] = lo;
    }
    __syncthreads();
    int start = se[0], end = se[1];
    float s = 0.f;
    for (int n = start + h; n < end; n += 4) s += bf2f(B[n * 128 + k]);
    red[h][k] = s;
    __syncthreads();
    if (h == 0) {
        float tot = red[0][k] + red[1][k] + red[2][k] + red[3][k];
        int cg = end - start;
        red[0][k] = tot / (float)(cg > 1 ? cg : 1);
    }
    __syncthreads();
    if (tid < 10) {
        float o = bl[tid];
        for (int j = 0; j < 128; j++) o = fmaf(red[0][j], Wl[j * 10 + tid], o);
        out[g * 10 + tid] = o;
    }
}

// ---------------- launch ----------------

extern "C" void kernel_launch(void* const* d_in, const int* in_sizes, int n_in,
                              void* d_out, int out_size, void* d_ws, size_t ws_size,
                              hipStream_t stream) {
    const float* x  = (const float*)d_in[0];
    const int* eidx = (const int*)d_in[1];
    const int* batch = (const int*)d_in[2];
    const float* W0 = (const float*)d_in[3];
    const float* b0 = (const float*)d_in[4];
    const float* W1 = (const float*)d_in[5];
    const float* b1 = (const float*)d_in[6];
    const float* W2 = (const float*)d_in[7];
    const float* b2 = (const float*)d_in[8];
    const float* Wl = (const float*)d_in[9];
    const float* bl = (const float*)d_in[10];

    int N = in_sizes[0] / 128;
    int E = in_sizes[1] / 2;
    int G = out_size / 10;
    const int* row = eidx;      // edge_index[0] = source
    const int* col = eidx + E;  // edge_index[1] = target

    char* w = (char*)d_ws;
    auto carve = [&](size_t bytes) -> void* {
        void* p = (void*)w;
        w += (bytes + 511) & ~(size_t)511;
        return p;
    };
    unsigned short* A  = (unsigned short*)carve((size_t)N * 128 * 2);  // bf16, slice-major
    unsigned short* Bb = (unsigned short*)carve((size_t)N * 128 * 2);  // bf16, row-major
    int*   cnt  = (int*)carve((size_t)N * 4);
    float* dinv = (float*)carve((size_t)N * 4);
    int*   ell  = (int*)carve((size_t)N * ELL_D * 4);
    unsigned short* WT1 = (unsigned short*)carve(16384 * 2);
    unsigned short* WT2 = (unsigned short*)carve(16384 * 2);

    int gb = (N + 63) / 64;

    hipMemsetAsync(cnt, 0, (size_t)N * 4, stream);
    k_prep_wt<<<2, 256, 0, stream>>>(W1, W2, WT1, WT2);
    // layer-1 gemm (f32 vector) overlapped with ownership ELL fill
    k_fused<<<FB + gb, 256, 0, stream>>>(x, W0, A, col, row, cnt, ell, N, E, gb);
    k_dinv_scaleA<<<(N * 64 + 255) / 256, 256, 0, stream>>>(cnt, dinv, A, N);

    int chunks = (N + 15) / 16;
    int ab = chunks * 8;
    int mb = (N + 63) / 64;
    k_agg<<<ab, 256, 0, stream>>>(A, cnt, ell, dinv, b0, Bb, N);
    // layer 2
    k_gemm_mfma<<<mb, 256, 0, stream>>>(Bb, WT1, dinv, A, N);
    k_agg<<<ab, 256, 0, stream>>>(A, cnt, ell, dinv, b1, Bb, N);
    // layer 3
    k_gemm_mfma<<<mb, 256, 0, stream>>>(Bb, WT2, dinv, A, N);
    k_agg<<<ab, 256, 0, stream>>>(A, cnt, ell, dinv, b2, Bb, N);
    // pool + head
    k_pool<<<G, 512, 0, stream>>>(Bb, batch, Wl, bl, (float*)d_out, N);
}

// Round 8
// 428.231 us; speedup vs baseline: 7.9573x; 7.9573x over previous
//
#include <hip/hip_runtime.h>
#include <hip/hip_bf16.h>

#define ELL_D 64   // max in-degree slots; Poisson(16) => P(deg>=64) ~ 2e-18/node
#define FK 128     // edge chunks; fill blocks = 8 ranges * FK chunks
#define FBT (8 * FK)

typedef __attribute__((ext_vector_type(8))) short short8;
typedef __attribute__((ext_vector_type(4))) float f32x4;

__device__ __forceinline__ unsigned short f2bf(float f) {
    __hip_bfloat16 h = __float2bfloat16(f);  // RNE
    return *(unsigned short*)&h;
}
__device__ __forceinline__ float bf2f(unsigned short u) {
    unsigned int v = ((unsigned int)u) << 16;
    return __uint_as_float(v);
}

// ---------------- gemm1 body (f32 vector): A(bf16 row-major) = x @ W0, unscaled ----------------

__device__ __forceinline__ void gemm_body(int bid, const float* __restrict__ H,
                                          const float* __restrict__ W, unsigned short* __restrict__ A,
                                          int N, float4* wl4) {
    int tid = threadIdx.x;
    const float4* __restrict__ W4 = (const float4*)W;
    int tc = tid & 15;
    int tr = tid >> 4;
    int rbase = bid * 64 + tr * 4;

    const float4* __restrict__ H4 = (const float4*)H;
    float acc[4][8] = {};
    int r[4];
#pragma unroll
    for (int j = 0; j < 4; j++) {
        int rr = rbase + j;
        r[j] = (rr < N) ? rr : (N - 1);
    }

    for (int p = 0; p < 2; p++) {
        if (p) __syncthreads();
#pragma unroll
        for (int i = 0; i < 8; i++) wl4[i * 256 + tid] = W4[p * 2048 + i * 256 + tid];
        __syncthreads();
#pragma unroll 4
        for (int k4 = 0; k4 < 16; k4++) {
            union { float4 v; float f[4]; } hu[4];
#pragma unroll
            for (int j = 0; j < 4; j++) hu[j].v = H4[r[j] * 32 + p * 16 + k4];
#pragma unroll
            for (int kk = 0; kk < 4; kk++) {
                float4 w0 = wl4[(k4 * 4 + kk) * 32 + tc];
                float4 w1 = wl4[(k4 * 4 + kk) * 32 + 16 + tc];
#pragma unroll
                for (int j = 0; j < 4; j++) {
                    float h = hu[j].f[kk];
                    acc[j][0] = fmaf(h, w0.x, acc[j][0]);
                    acc[j][1] = fmaf(h, w0.y, acc[j][1]);
                    acc[j][2] = fmaf(h, w0.z, acc[j][2]);
                    acc[j][3] = fmaf(h, w0.w, acc[j][3]);
                    acc[j][4] = fmaf(h, w1.x, acc[j][4]);
                    acc[j][5] = fmaf(h, w1.y, acc[j][5]);
                    acc[j][6] = fmaf(h, w1.z, acc[j][6]);
                    acc[j][7] = fmaf(h, w1.w, acc[j][7]);
                }
            }
        }
    }

    ushort4* __restrict__ A4 = (ushort4*)A;
#pragma unroll
    for (int j = 0; j < 4; j++) {
        int rr = rbase + j;
        if (rr < N) {
            A4[rr * 32 + tc]      = make_ushort4(f2bf(acc[j][0]), f2bf(acc[j][1]), f2bf(acc[j][2]), f2bf(acc[j][3]));
            A4[rr * 32 + 16 + tc] = make_ushort4(f2bf(acc[j][4]), f2bf(acc[j][5]), f2bf(acc[j][6]), f2bf(acc[j][7]));
        }
    }
}

// ---------------- ownership fill: 8 ranges x FK chunks; range r pinned to XCD r via blockIdx%8 ----------------
// Block (r,k): reads edge chunk k, keeps edges with dest in range r. All atomics+scatters
// for range r land in one XCD's L2 (3.2MB ell slice + 50KB cnt slice).

__device__ __forceinline__ void fill_own_body(int b, const int* __restrict__ col, const int* __restrict__ row,
                                              int* __restrict__ cnt, int* __restrict__ ell, int E, int N) {
    int r = b & 7, k = b >> 3;
    int nr = (N + 7) / 8;
    int lo = r * nr;
    int hi = lo + nr; if (hi > N) hi = N;
    int tid = threadIdx.x;
    int E4 = E >> 2;
    int chunk = (E4 + FK - 1) / FK;
    int q0 = k * chunk;
    int q1 = q0 + chunk; if (q1 > E4) q1 = E4;
    const int4* __restrict__ c4p = (const int4*)col;
    const int4* __restrict__ r4p = (const int4*)row;
    for (int q = q0 + tid; q < q1; q += 256) {
        int4 c4 = c4p[q];
        int4 r4 = r4p[q];
        if (c4.x >= lo && c4.x < hi) { int p = atomicAdd(&cnt[c4.x], 1) & 63; ell[c4.x * ELL_D + p] = r4.x; }
        if (c4.y >= lo && c4.y < hi) { int p = atomicAdd(&cnt[c4.y], 1) & 63; ell[c4.y * ELL_D + p] = r4.y; }
        if (c4.z >= lo && c4.z < hi) { int p = atomicAdd(&cnt[c4.z], 1) & 63; ell[c4.z * ELL_D + p] = r4.z; }
        if (c4.w >= lo && c4.w < hi) { int p = atomicAdd(&cnt[c4.w], 1) & 63; ell[c4.w * ELL_D + p] = r4.w; }
    }
    if (k == FK - 1) {  // tail edges (E not multiple of 4)
        int rem = E & 3;
        if (tid < rem) {
            int e = E4 * 4 + tid;
            int c = col[e];
            if (c >= lo && c < hi) { int p = atomicAdd(&cnt[c], 1) & 63; ell[c * ELL_D + p] = row[e]; }
        }
    }
}

__global__ __launch_bounds__(256) void k_fused(const float* __restrict__ H, const float* __restrict__ W,
                                               unsigned short* __restrict__ A,
                                               const int* __restrict__ col, const int* __restrict__ row,
                                               int* __restrict__ cnt, int* __restrict__ ell,
                                               int N, int E, int gb) {
    __shared__ float4 wl4[2048];  // 32KB (gemm blocks only)
    if (blockIdx.x < FBT) {
        fill_own_body(blockIdx.x, col, row, cnt, ell, E, N);
    } else {
        int gbid = blockIdx.x - FBT;
        if (gbid < gb) gemm_body(gbid, H, W, A, N, wl4);
    }
}

// ---------------- W prep: WT (bf16, transposed) for layers 2,3 ----------------
__global__ __launch_bounds__(256) void k_prep_wt(const float* __restrict__ W1, const float* __restrict__ W2,
                                                 unsigned short* __restrict__ WT1, unsigned short* __restrict__ WT2) {
    const float* W = blockIdx.x ? W2 : W1;
    unsigned short* WT = blockIdx.x ? WT2 : WT1;
    for (int i = threadIdx.x; i < 16384; i += 256) {
        int c = i >> 7, k = i & 127;
        WT[i] = f2bf(W[k * 128 + c]);  // WT[c][k] = W[k][c]
    }
}

// ---------------- dinv + scale layer-1 A in place: A[n] *= dinv[n] ----------------
__global__ __launch_bounds__(256) void k_dinv_scaleA(const int* __restrict__ cnt, float* __restrict__ dinv,
                                                     unsigned short* __restrict__ A, int N) {
    int node = blockIdx.x * 8 + (threadIdx.x >> 5);
    int li = threadIdx.x & 31;
    if (node >= N) return;
    float dn = 1.0f / sqrtf((float)(cnt[node] + 1));
    if (li == 0) dinv[node] = dn;
    ushort4* Ap = (ushort4*)A + (size_t)node * 32 + li;
    ushort4 v = *Ap;
    v.x = f2bf(bf2f(v.x) * dn);
    v.y = f2bf(bf2f(v.y) * dn);
    v.z = f2bf(bf2f(v.z) * dn);
    v.w = f2bf(bf2f(v.w) * dn);
    *Ap = v;
}

// ---------------- MFMA GEMM (layers 2,3): A' = bf16((Bb @ W) * dinv[row]) ----------------

__global__ __launch_bounds__(256) void k_gemm_mfma(const unsigned short* __restrict__ H,
                                                   const unsigned short* __restrict__ WT,
                                                   const float* __restrict__ dinv,
                                                   unsigned short* __restrict__ A, int N) {
    __shared__ float ep[4 * 16 * 132];  // per-wave 16x128 f32, row stride 132
    int tid = threadIdx.x, w = tid >> 6, l = tid & 63;
    int rbase = blockIdx.x * 64 + w * 16;
    int lrow = l & 15, lk = l >> 4;

    int r = rbase + lrow;
    if (r >= N) r = N - 1;
    const short8* __restrict__ Hp = (const short8*)(H + (size_t)r * 128);
    short8 af[4];
#pragma unroll
    for (int kc = 0; kc < 4; kc++) af[kc] = Hp[kc * 4 + lk];

    f32x4 acc[8];
#pragma unroll
    for (int t = 0; t < 8; t++) {
        f32x4 a = {0.f, 0.f, 0.f, 0.f};
        const short8* __restrict__ Wp = (const short8*)(WT + (size_t)(t * 16 + lrow) * 128);
#pragma unroll
        for (int kc = 0; kc < 4; kc++) {
            short8 bf = Wp[kc * 4 + lk];
            a = __builtin_amdgcn_mfma_f32_16x16x32_bf16(af[kc], bf, a, 0, 0, 0);
        }
        acc[t] = a;
    }

    float* base = ep + w * 2112;
#pragma unroll
    for (int t = 0; t < 8; t++)
#pragma unroll
        for (int j = 0; j < 4; j++)
            base[(4 * lk + j) * 132 + t * 16 + lrow] = acc[t][j];
    __syncthreads();

    int row16 = l >> 2, c0 = (l & 3) * 32;
    int orow = rbase + row16;
    if (orow < N) {
        float dn = dinv[orow];
        const float* src = base + row16 * 132 + c0;
        unsigned short* dst = A + (size_t)orow * 128 + c0;
#pragma unroll
        for (int q = 0; q < 4; q++) {
            union { short8 s8; unsigned short u[8]; } pk;
#pragma unroll
            for (int e = 0; e < 8; e++) pk.u[e] = f2bf(src[q * 8 + e] * dn);
            *(short8*)(dst + q * 8) = pk.s8;
        }
    }
}

// ---------------- Aggregation (R6 form: wave per node, 256B bf16 row gathers) ----------------

__global__ __launch_bounds__(256) void k_agg(const unsigned short* __restrict__ A, const int* __restrict__ cnt,
                                             const int* __restrict__ ell, const float* __restrict__ dinv,
                                             const float* __restrict__ bias, unsigned short* __restrict__ Bout, int N) {
    int wid = blockIdx.x * 4 + (threadIdx.x >> 6);
    int lane = threadIdx.x & 63;
    if (wid >= N) return;
    int hi = lane >> 5, li = lane & 31;
    const ushort4* __restrict__ A4 = (const ushort4*)A;
    int deg = cnt[wid];
    float dn = dinv[wid];
    const int* __restrict__ lst = ell + wid * ELL_D;

    int total = deg + 1;          // + virtual self edge at slot==deg
    int pairs = (total + 1) >> 1;

    float4 a0 = {0,0,0,0}, a1 = {0,0,0,0}, a2 = {0,0,0,0}, a3 = {0,0,0,0};
    int i = 0;
    for (; i + 4 <= pairs; i += 4) {
        int s0 = 2 * i + hi, s1 = s0 + 2, s2 = s0 + 4, s3 = s0 + 6;
        int e0 = (s0 < deg) ? lst[s0] : wid;
        int e1 = (s1 < deg) ? lst[s1] : wid;
        int e2 = (s2 < deg) ? lst[s2] : wid;
        int e3 = (s3 < deg) ? lst[s3] : wid;
        float m0 = (s0 < total) ? 1.f : 0.f;
        float m1 = (s1 < total) ? 1.f : 0.f;
        float m2 = (s2 < total) ? 1.f : 0.f;
        float m3 = (s3 < total) ? 1.f : 0.f;
        ushort4 v0 = A4[e0 * 32 + li];
        ushort4 v1 = A4[e1 * 32 + li];
        ushort4 v2 = A4[e2 * 32 + li];
        ushort4 v3 = A4[e3 * 32 + li];
        a0.x = fmaf(bf2f(v0.x), m0, a0.x); a0.y = fmaf(bf2f(v0.y), m0, a0.y);
        a0.z = fmaf(bf2f(v0.z), m0, a0.z); a0.w = fmaf(bf2f(v0.w), m0, a0.w);
        a1.x = fmaf(bf2f(v1.x), m1, a1.x); a1.y = fmaf(bf2f(v1.y), m1, a1.y);
        a1.z = fmaf(bf2f(v1.z), m1, a1.z); a1.w = fmaf(bf2f(v1.w), m1, a1.w);
        a2.x = fmaf(bf2f(v2.x), m2, a2.x); a2.y = fmaf(bf2f(v2.y), m2, a2.y);
        a2.z = fmaf(bf2f(v2.z), m2, a2.z); a2.w = fmaf(bf2f(v2.w), m2, a2.w);
        a3.x = fmaf(bf2f(v3.x), m3, a3.x); a3.y = fmaf(bf2f(v3.y), m3, a3.y);
        a3.z = fmaf(bf2f(v3.z), m3, a3.z); a3.w = fmaf(bf2f(v3.w), m3, a3.w);
    }
    for (; i < pairs; i++) {
        int s0 = 2 * i + hi;
        int e0 = (s0 < deg) ? lst[s0] : wid;
        float m0 = (s0 < total) ? 1.f : 0.f;
        ushort4 v0 = A4[e0 * 32 + li];
        a0.x = fmaf(bf2f(v0.x), m0, a0.x); a0.y = fmaf(bf2f(v0.y), m0, a0.y);
        a0.z = fmaf(bf2f(v0.z), m0, a0.z); a0.w = fmaf(bf2f(v0.w), m0, a0.w);
    }
    a0.x = (a0.x + a1.x) + (a2.x + a3.x);
    a0.y = (a0.y + a1.y) + (a2.y + a3.y);
    a0.z = (a0.z + a1.z) + (a2.z + a3.z);
    a0.w = (a0.w + a1.w) + (a2.w + a3.w);
    a0.x += __shfl_xor(a0.x, 32, 64);
    a0.y += __shfl_xor(a0.y, 32, 64);
    a0.z += __shfl_xor(a0.z, 32, 64);
    a0.w += __shfl_xor(a0.w, 32, 64);

    if (hi == 0) {
        const float4* __restrict__ b4 = (const float4*)bias;
        float4 bb = b4[li];
        ushort4 o;
        o.x = f2bf(fmaxf(fmaf(a0.x, dn, bb.x), 0.f));
        o.y = f2bf(fmaxf(fmaf(a0.y, dn, bb.y), 0.f));
        o.z = f2bf(fmaxf(fmaf(a0.z, dn, bb.z), 0.f));
        o.w = f2bf(fmaxf(fmaf(a0.w, dn, bb.w), 0.f));
        ((ushort4*)Bout)[wid * 32 + li] = o;
    }
}

// ---------------- Pool (mean per graph, sorted batch) + head; B is bf16 ----------------

__global__ __launch_bounds__(512) void k_pool(const unsigned short* __restrict__ B, const int* __restrict__ batch,
                                              const float* __restrict__ Wl, const float* __restrict__ bl,
                                              float* __restrict__ out, int N) {
    int g = blockIdx.x;
    int tid = threadIdx.x;
    int k = tid & 127, h = tid >> 7;  // h in 0..3
    __shared__ int se[2];
    __shared__ float red[4][128];
    if (tid < 2) {
        int target = g + tid;  // lower_bound(batch, target)
        int lo = 0, hi = N;
        while (lo < hi) {
            int mid = (lo + hi) >> 1;
            if (batch[mid] < target) lo = mid + 1; else hi = mid;
        }
        se[tid] = lo;
    }
    __syncthreads();
    int start = se[0], end = se[1];
    float s = 0.f;
    for (int n = start + h; n < end; n += 4) s += bf2f(B[n * 128 + k]);
    red[h][k] = s;
    __syncthreads();
    if (h == 0) {
        float tot = red[0][k] + red[1][k] + red[2][k] + red[3][k];
        int cg = end - start;
        red[0][k] = tot / (float)(cg > 1 ? cg : 1);
    }
    __syncthreads();
    if (tid < 10) {
        float o = bl[tid];
        for (int j = 0; j < 128; j++) o = fmaf(red[0][j], Wl[j * 10 + tid], o);
        out[g * 10 + tid] = o;
    }
}

// ---------------- launch ----------------

extern "C" void kernel_launch(void* const* d_in, const int* in_sizes, int n_in,
                              void* d_out, int out_size, void* d_ws, size_t ws_size,
                              hipStream_t stream) {
    const float* x  = (const float*)d_in[0];
    const int* eidx = (const int*)d_in[1];
    const int* batch = (const int*)d_in[2];
    const float* W0 = (const float*)d_in[3];
    const float* b0 = (const float*)d_in[4];
    const float* W1 = (const float*)d_in[5];
    const float* b1 = (const float*)d_in[6];
    const float* W2 = (const float*)d_in[7];
    const float* b2 = (const float*)d_in[8];
    const float* Wl = (const float*)d_in[9];
    const float* bl = (const float*)d_in[10];

    int N = in_sizes[0] / 128;
    int E = in_sizes[1] / 2;
    int G = out_size / 10;
    const int* row = eidx;      // edge_index[0] = source
    const int* col = eidx + E;  // edge_index[1] = target

    char* w = (char*)d_ws;
    auto carve = [&](size_t bytes) -> void* {
        void* p = (void*)w;
        w += (bytes + 511) & ~(size_t)511;
        return p;
    };
    unsigned short* A  = (unsigned short*)carve((size_t)N * 128 * 2);  // bf16 row-major
    unsigned short* Bb = (unsigned short*)carve((size_t)N * 128 * 2);  // bf16 row-major
    int*   cnt  = (int*)carve((size_t)N * 4);
    float* dinv = (float*)carve((size_t)N * 4);
    int*   ell  = (int*)carve((size_t)N * ELL_D * 4);
    unsigned short* WT1 = (unsigned short*)carve(16384 * 2);
    unsigned short* WT2 = (unsigned short*)carve(16384 * 2);

    int gb = (N + 63) / 64;

    hipMemsetAsync(cnt, 0, (size_t)N * 4, stream);
    k_prep_wt<<<2, 256, 0, stream>>>(W1, W2, WT1, WT2);
    // layer-1 gemm (f32 vector) overlapped with XCD-pinned ownership fill
    k_fused<<<FBT + gb, 256, 0, stream>>>(x, W0, A, col, row, cnt, ell, N, E, gb);
    k_dinv_scaleA<<<(N + 7) / 8, 256, 0, stream>>>(cnt, dinv, A, N);

    int ab = (N + 3) / 4;
    int mb = (N + 63) / 64;
    k_agg<<<ab, 256, 0, stream>>>(A, cnt, ell, dinv, b0, Bb, N);
    // layer 2
    k_gemm_mfma<<<mb, 256, 0, stream>>>(Bb, WT1, dinv, A, N);
    k_agg<<<ab, 256, 0, stream>>>(A, cnt, ell, dinv, b1, Bb, N);
    // layer 3
    k_gemm_mfma<<<mb, 256, 0, stream>>>(Bb, WT2, dinv, A, N);
    k_agg<<<ab, 256, 0, stream>>>(A, cnt, ell, dinv, b2, Bb, N);
    // pool + head
    k_pool<<<G, 512, 0, stream>>>(Bb, batch, Wl, bl, (float*)d_out, N);
}